// Round 1
// baseline (1112.766 us; speedup 1.0000x reference)
//
#include <hip/hip_runtime.h>
#include <math.h>

// VectorQuantizer: x [32,32,32,256] f32, embedding [256,4096] f32
// out: quantized_st [8388608] f32  ++  loss [1] f32
//
// Round 1: correctness-first fp32 implementation.
//  - dist mimics reference: (||x||^2 + ||e||^2) - 2*sim, fp32 FMA accum
//  - argmin with lowest-index tie-break (matches jnp.argmin)
//  - GEMM-argmin: 64 rows x 64 codes tile, 4x4 micro-tile, x-tile resident in LDS

#define N_ROWS 32768
#define DIM    256
#define KCODES 4096
#define NPART  (N_ROWS / 4)

// workspace layout (in floats)
#define WS_ET   0                      // transposed embedding [4096][256]
#define WS_BN   (KCODES * DIM)         // code norms  [4096]
#define WS_AN   (WS_BN + KCODES)       // row norms   [32768]
#define WS_IDX  (WS_AN + N_ROWS)       // argmin idx  [32768] (int)
#define WS_PART (WS_IDX + N_ROWS)      // loss partials [8192]

// ---------------------------------------------------------------- transpose
// e [256][4096] -> et [4096][256], 32x32 tiles
__global__ void vq_transpose(const float* __restrict__ e, float* __restrict__ et) {
    __shared__ float tile[32][33];
    int x = threadIdx.x & 31;
    int y = threadIdx.x >> 5;              // 0..7
    int k0 = blockIdx.x * 32;              // 0..4095
    int d0 = blockIdx.y * 32;              // 0..255
#pragma unroll
    for (int yy = 0; yy < 32; yy += 8)
        tile[y + yy][x] = e[(d0 + y + yy) * KCODES + k0 + x];
    __syncthreads();
#pragma unroll
    for (int yy = 0; yy < 32; yy += 8)
        et[(k0 + y + yy) * DIM + d0 + x] = tile[x][y + yy];
}

// ---------------------------------------------------------------- row norms
// one wave per row of length 256: lane reads float4, xor-tree reduce (pairwise-ish)
__global__ void vq_rownorm(const float* __restrict__ src, float* __restrict__ out, int nrows) {
    int w    = threadIdx.x >> 6;
    int lane = threadIdx.x & 63;
    int row  = blockIdx.x * 4 + w;
    if (row >= nrows) return;
    float4 v = *(const float4*)&src[row * DIM + lane * 4];
    float  s = v.x * v.x + v.y * v.y + v.z * v.z + v.w * v.w;
#pragma unroll
    for (int m = 1; m < 64; m <<= 1) s += __shfl_xor(s, m);
    if (lane == 0) out[row] = s;
}

// ---------------------------------------------------------------- main: GEMM + argmin
// block: 256 threads (16 tx x 16 ty). Tile: 64 rows x 64 codes, 4x4 micro-tile.
// x-tile (64 rows x 256 D) staged transposed in LDS once; B-tile restaged per chunk.
__global__ __launch_bounds__(256, 2) void vq_argmin(
    const float* __restrict__ x, const float* __restrict__ e,
    const float* __restrict__ An, const float* __restrict__ Bn,
    int* __restrict__ idxOut)
{
    __shared__ float As[DIM][68];   // transposed x tile, padded (16B-aligned rows)
    __shared__ float Bs[32][64];    // embedding chunk [d][k]

    const int tid = threadIdx.x;
    const int tx = tid & 15, ty = tid >> 4;
    const int row0 = blockIdx.x * 64;

    // ---- stage As (transposed): 64 rows x 256 d
    {
        const int al = tid & 7;          // d-group (x4)
        const int am = tid >> 3;         // row 0..31
#pragma unroll
        for (int d0 = 0; d0 < DIM; d0 += 32) {
            const int d = d0 + al * 4;
#pragma unroll
            for (int half = 0; half < 2; ++half) {
                const int m = am + half * 32;
                float4 v = *(const float4*)&x[(size_t)(row0 + m) * DIM + d];
                As[d + 0][m] = v.x;
                As[d + 1][m] = v.y;
                As[d + 2][m] = v.z;
                As[d + 3][m] = v.w;
            }
        }
    }

    float aN[4];
#pragma unroll
    for (int i = 0; i < 4; ++i) aN[i] = An[row0 + ty * 4 + i];

    float bestD[4];
    int   bestK[4];
#pragma unroll
    for (int i = 0; i < 4; ++i) { bestD[i] = INFINITY; bestK[i] = 0; }

    __syncthreads();

    for (int c0 = 0; c0 < KCODES; c0 += 64) {
        float acc[4][4];
#pragma unroll
        for (int i = 0; i < 4; ++i)
#pragma unroll
            for (int j = 0; j < 4; ++j) acc[i][j] = 0.0f;

        for (int d0 = 0; d0 < DIM; d0 += 32) {
            __syncthreads();   // protect Bs from previous iteration's readers
            {
                const int bl = tid & 15, bm = tid >> 4;
                *(float4*)&Bs[bm][bl * 4] =
                    *(const float4*)&e[(size_t)(d0 + bm) * KCODES + c0 + bl * 4];
                *(float4*)&Bs[bm + 16][bl * 4] =
                    *(const float4*)&e[(size_t)(d0 + bm + 16) * KCODES + c0 + bl * 4];
            }
            __syncthreads();
#pragma unroll
            for (int d = 0; d < 32; ++d) {
                float4 av = *(const float4*)&As[d0 + d][ty * 4];
                float4 bv = *(const float4*)&Bs[d][tx * 4];
                acc[0][0] = fmaf(av.x, bv.x, acc[0][0]);
                acc[0][1] = fmaf(av.x, bv.y, acc[0][1]);
                acc[0][2] = fmaf(av.x, bv.z, acc[0][2]);
                acc[0][3] = fmaf(av.x, bv.w, acc[0][3]);
                acc[1][0] = fmaf(av.y, bv.x, acc[1][0]);
                acc[1][1] = fmaf(av.y, bv.y, acc[1][1]);
                acc[1][2] = fmaf(av.y, bv.z, acc[1][2]);
                acc[1][3] = fmaf(av.y, bv.w, acc[1][3]);
                acc[2][0] = fmaf(av.z, bv.x, acc[2][0]);
                acc[2][1] = fmaf(av.z, bv.y, acc[2][1]);
                acc[2][2] = fmaf(av.z, bv.z, acc[2][2]);
                acc[2][3] = fmaf(av.z, bv.w, acc[2][3]);
                acc[3][0] = fmaf(av.w, bv.x, acc[3][0]);
                acc[3][1] = fmaf(av.w, bv.y, acc[3][1]);
                acc[3][2] = fmaf(av.w, bv.z, acc[3][2]);
                acc[3][3] = fmaf(av.w, bv.w, acc[3][3]);
            }
        }

        // epilogue: dist = (||x||^2 + ||e||^2) - 2*sim ; running argmin
        float4 bn = *(const float4*)&Bn[c0 + tx * 4];
        float bnv[4] = { bn.x, bn.y, bn.z, bn.w };
#pragma unroll
        for (int i = 0; i < 4; ++i) {
#pragma unroll
            for (int j = 0; j < 4; ++j) {
                float t    = aN[i] + bnv[j];
                float dist = t - 2.0f * acc[i][j];
                int   k    = c0 + tx * 4 + j;
                if (dist < bestD[i]) { bestD[i] = dist; bestK[i] = k; }
            }
        }
    }

    // ---- cross-thread reduce (16 tx threads share each row), lowest-index ties
    __syncthreads();
    float* redD = (float*)Bs;          // 64*16 floats = 4 KB (Bs dead now)
    int*   redK = (int*)&As[0][0];     // reuse As       (As dead now)
#pragma unroll
    for (int i = 0; i < 4; ++i) {
        const int r = ty * 4 + i;
        redD[r * 16 + tx] = bestD[i];
        redK[r * 16 + tx] = bestK[i];
    }
    __syncthreads();
    if (tid < 64) {
        float bd = INFINITY;
        int   bk = 0x7fffffff;
#pragma unroll
        for (int t = 0; t < 16; ++t) {
            float d = redD[tid * 16 + t];
            int   k = redK[tid * 16 + t];
            if (d < bd || (d == bd && k < bk)) { bd = d; bk = k; }
        }
        idxOut[row0 + tid] = bk;
    }
}

// ---------------------------------------------------------------- gather + loss partials
__global__ void vq_gather(const float* __restrict__ x, const float* __restrict__ et,
                          const int* __restrict__ idx, float* __restrict__ out,
                          float* __restrict__ part) {
    __shared__ float wsum[4];
    int w    = threadIdx.x >> 6;
    int lane = threadIdx.x & 63;
    int row  = blockIdx.x * 4 + w;
    int k    = idx[row];
    float4 q  = *(const float4*)&et[(size_t)k * DIM + lane * 4];
    float4 xv = *(const float4*)&x[(size_t)row * DIM + lane * 4];
    *(float4*)&out[(size_t)row * DIM + lane * 4] = q;
    float d0 = q.x - xv.x, d1 = q.y - xv.y, d2 = q.z - xv.z, d3 = q.w - xv.w;
    float s = d0 * d0 + d1 * d1 + d2 * d2 + d3 * d3;
#pragma unroll
    for (int m = 1; m < 64; m <<= 1) s += __shfl_xor(s, m);
    if (lane == 0) wsum[w] = s;
    __syncthreads();
    if (threadIdx.x == 0) part[blockIdx.x] = wsum[0] + wsum[1] + wsum[2] + wsum[3];
}

// ---------------------------------------------------------------- finalize loss (deterministic)
__global__ void vq_finalize(const float* __restrict__ part, float* __restrict__ lossOut) {
    __shared__ float sm[256];
    float s = 0.0f;
    for (int i = threadIdx.x; i < NPART; i += 256) s += part[i];
    sm[threadIdx.x] = s;
    __syncthreads();
    for (int st = 128; st > 0; st >>= 1) {
        if (threadIdx.x < st) sm[threadIdx.x] += sm[threadIdx.x + st];
        __syncthreads();
    }
    if (threadIdx.x == 0)
        lossOut[0] = 1.25f * (sm[0] / 8388608.0f);   // (1+BETA) * mean
}

// ---------------------------------------------------------------- launch
extern "C" void kernel_launch(void* const* d_in, const int* in_sizes, int n_in,
                              void* d_out, int out_size, void* d_ws, size_t ws_size,
                              hipStream_t stream) {
    const float* x = (const float*)d_in[0];   // [32768, 256]
    const float* e = (const float*)d_in[1];   // [256, 4096]
    float* out = (float*)d_out;
    float* ws  = (float*)d_ws;

    float* et   = ws + WS_ET;
    float* bn   = ws + WS_BN;
    float* an   = ws + WS_AN;
    int*   idx  = (int*)(ws + WS_IDX);
    float* part = ws + WS_PART;

    vq_transpose<<<dim3(KCODES / 32, DIM / 32), 256, 0, stream>>>(e, et);
    vq_rownorm<<<N_ROWS / 4, 256, 0, stream>>>(x, an, N_ROWS);
    vq_rownorm<<<KCODES / 4, 256, 0, stream>>>(et, bn, KCODES);
    vq_argmin<<<N_ROWS / 64, 256, 0, stream>>>(x, e, an, bn, idx);
    vq_gather<<<N_ROWS / 4, 256, 0, stream>>>(x, et, idx, out, part);
    vq_finalize<<<1, 256, 0, stream>>>(part, out + (size_t)N_ROWS * DIM);
}

// Round 2
// 410.457 us; speedup vs baseline: 2.7110x; 2.7110x over previous
//
#include <hip/hip_runtime.h>
#include <math.h>

typedef _Float16 f16;
typedef f16 f16x8 __attribute__((ext_vector_type(8)));
typedef float f32x4 __attribute__((ext_vector_type(4)));

#define N_ROWS 32768
#define DIM    256
#define KCODES 4096

// ws layout (float units)
#define WS_ET    0                           // et [4096][256] f32
#define WS_BN    (WS_ET + KCODES*DIM)        // code norms [4096]
#define WS_AN    (WS_BN + KCODES)            // row norms [32768]
#define WS_PART  (WS_AN + N_ROWS)            // loss partials [8192]
#define WS_BEST  (WS_PART + 8192)            // u64 bests [32768] = 65536 floats
#define WS_BP    (WS_BEST + 65536)           // B' f16 [4096*1024] = 2097152 floats (8 MB)

// ---------------------------------------------------------------- helpers
__device__ __forceinline__ void gload16(const void* g, void* l) {
#if __has_builtin(__builtin_amdgcn_global_load_lds)
    __builtin_amdgcn_global_load_lds(
        (const __attribute__((address_space(1))) unsigned int*)g,
        (__attribute__((address_space(3))) unsigned int*)l, 16, 0, 0);
#else
    *(float4*)l = *(const float4*)g;
#endif
}

__device__ __forceinline__ uint32_t split_word_hh(float s, float* rem) {
    f16 h = (f16)s;
    *rem = s - (float)h;
    uint16_t hb = __builtin_bit_cast(uint16_t, h);
    return (uint32_t)hb * 0x10001u;
}

// ---------------------------------------------------------------- transpose (for gather + bn)
__global__ void vq_transpose(const float* __restrict__ e, float* __restrict__ et) {
    __shared__ float tile[32][33];
    int x = threadIdx.x & 31;
    int y = threadIdx.x >> 5;
    int k0 = blockIdx.x * 32;
    int d0 = blockIdx.y * 32;
#pragma unroll
    for (int yy = 0; yy < 32; yy += 8)
        tile[y + yy][x] = e[(d0 + y + yy) * KCODES + k0 + x];
    __syncthreads();
#pragma unroll
    for (int yy = 0; yy < 32; yy += 8)
        et[(k0 + y + yy) * DIM + d0 + x] = tile[x][y + yy];
}

// ---------------------------------------------------------------- row norms
__global__ void vq_rownorm(const float* __restrict__ src, float* __restrict__ out, int nrows) {
    int w    = threadIdx.x >> 6;
    int lane = threadIdx.x & 63;
    int row  = blockIdx.x * 4 + w;
    if (row >= nrows) return;
    float4 v = *(const float4*)&src[row * DIM + lane * 4];
    float  s = v.x * v.x + v.y * v.y + v.z * v.z + v.w * v.w;
#pragma unroll
    for (int m = 1; m < 64; m <<= 1) s += __shfl_xor(s, m);
    if (lane == 0) out[row] = s;
}

// ---------------------------------------------------------------- B' prep
// Build B' [32 jb][16 kc][128 n_loc][64 kk] f16, swizzled exactly as the LDS
// tile image: byte-in-plane = n_loc*128 + ((kk*2) ^ ((n_loc&7)<<4)).
// Expanded kk = 4*dloc + p -> [eh, el, eh, el] of e[d][n]*1024.
__global__ void vq_prep_b(const float* __restrict__ e, f16* __restrict__ Bp) {
    __shared__ float lt[128][33];   // [n_loc][dd]
    const int t  = threadIdx.x;
    const int nb = blockIdx.x & 31;   // code panel (128)
    const int db = blockIdx.x >> 5;   // d panel (32)
    const int n0 = nb * 128, d0 = db * 32;
    // coalesced load e[d0..d0+31][n0..n0+127], transpose into LDS
#pragma unroll
    for (int it = 0; it < 4; ++it) {
        int dd = (t >> 5) + it * 8;
        int nn = (t & 31) * 4;
        float4 v = *(const float4*)&e[(size_t)(d0 + dd) * KCODES + n0 + nn];
        lt[nn + 0][dd] = v.x;
        lt[nn + 1][dd] = v.y;
        lt[nn + 2][dd] = v.z;
        lt[nn + 3][dd] = v.w;
    }
    __syncthreads();
    // write 32 KB: [2 kc_loc][128 n_loc][128 B], fully coalesced
    char* region = (char*)Bp + (size_t)nb * 262144 + (size_t)db * 32768;
#pragma unroll
    for (int it = 0; it < 8; ++it) {
        int pos    = it * 4096 + t * 16;
        int kc_loc = pos >> 14;
        int o      = pos & 16383;
        int n_loc  = o >> 7;
        int bcp    = o & 127;
        int kkb    = (bcp ^ ((n_loc & 7) << 4)) >> 1;  // multiple of 8
        int da     = kkb >> 2;                          // even dloc
        int dd     = kc_loc * 16 + da;
        float r1, r2;
        uint32_t w1h = split_word_hh(lt[n_loc][dd]     * 1024.0f, &r1);
        uint32_t w2h = split_word_hh(lt[n_loc][dd + 1] * 1024.0f, &r2);
        f16 l1 = (f16)r1, l2 = (f16)r2;
        uint16_t l1b = __builtin_bit_cast(uint16_t, l1);
        uint16_t l2b = __builtin_bit_cast(uint16_t, l2);
        // word layout per d: [ (eh|eh), ... ] wait: entries 4d+{0,1}=eh,el ; {2,3}=eh,el
        uint16_t h1b = (uint16_t)(w1h & 0xffffu);
        uint16_t h2b = (uint16_t)(w2h & 0xffffu);
        uint32_t wa = (uint32_t)h1b | ((uint32_t)l1b << 16);
        uint32_t wb = (uint32_t)h2b | ((uint32_t)l2b << 16);
        uint4 out;
        out.x = wa; out.y = wa; out.z = wb; out.w = wb;
        // region layout: kc_loc plane at kc_loc*16384; n_loc*128 + bcp
        *(uint4*)(region + (size_t)kc_loc * 16384 + n_loc * 128 + bcp) = out;
    }
}

// ---------------------------------------------------------------- init bests
__global__ void vq_init(unsigned long long* __restrict__ bests) {
    int i = blockIdx.x * 256 + threadIdx.x;
    if (i < N_ROWS) bests[i] = ~0ull;
}

// ---------------------------------------------------------------- main MFMA GEMM + argmin
// 128 rows x 128 codes per block, K'=1024 expanded, BK=64 per chunk.
// 4 waves 2x2, each 64x64 via 4x4 frags of mfma_f32_16x16x32_f16.
__global__ __launch_bounds__(256) void vq_main(
    const float* __restrict__ x, const f16* __restrict__ Bp,
    const float* __restrict__ An, const float* __restrict__ Bn,
    unsigned long long* __restrict__ bests)
{
    __shared__ __align__(16) char AsB[128 * 128];  // [m][64 f16 = 128B] swizzled
    __shared__ __align__(16) char BsB[128 * 128];  // [n][64 f16 = 128B] swizzled

    const int tid  = threadIdx.x;
    const int wid  = tid >> 6, lane = tid & 63;
    const int wr   = wid >> 1, wc = wid & 1;
    const int rb   = blockIdx.x & 255, jb = blockIdx.x >> 8;
    const int row0 = rb * 128, c0 = jb * 128;

    const int hi = lane >> 4, ln = lane & 15;
    const int sx = (lane & 7) << 4;

    // A staging decomposition: thread -> (tm row, tq d-group)
    const int tq = tid & 3, tm = tid >> 2;
    const int aswz = (tm & 7) << 4;

    f32x4 acc[4][4] = {};

    const char* bsrc = (const char*)Bp + (size_t)jb * 262144;

    for (int kc = 0; kc < 16; ++kc) {
        const int d0 = kc * 16;
        // issue x loads early (global->reg, no LDS hazard)
        float4 xv0 = *(const float4*)&x[(size_t)(row0 + tm) * DIM + d0 + tq * 4];
        float4 xv1 = *(const float4*)&x[(size_t)(row0 + tm + 64) * DIM + d0 + tq * 4];

        __syncthreads();   // previous compute done reading LDS

        // B: linear copy of pre-swizzled 16 KB image
#pragma unroll
        for (int it = 0; it < 4; ++it)
            gload16(bsrc + (size_t)kc * 16384 + it * 4096 + tid * 16,
                    BsB + it * 4096 + tid * 16);

        // A: convert fp32 -> (h,l) f16 pairs, expanded [h,h,l,l], swizzled writes
#pragma unroll
        for (int half = 0; half < 2; ++half) {
            float4 v = half ? xv1 : xv0;
            int m = tm + half * 64;
            float vs[4] = { v.x, v.y, v.z, v.w };
            uint32_t w[8];
#pragma unroll
            for (int j = 0; j < 4; ++j) {
                float s = vs[j] * 1024.0f;
                float rem;
                w[2 * j] = split_word_hh(s, &rem);
                f16 l = (f16)rem;
                uint16_t lb = __builtin_bit_cast(uint16_t, l);
                w[2 * j + 1] = (uint32_t)lb * 0x10001u;
            }
            char* basep = AsB + m * 128;
            *(uint4*)(basep + ((32 * tq) ^ aswz))      = *(uint4*)&w[0];
            *(uint4*)(basep + ((32 * tq + 16) ^ aswz)) = *(uint4*)&w[4];
        }

        __syncthreads();   // staging visible (compiler drains vmcnt/lgkmcnt)

#pragma unroll
        for (int ks = 0; ks < 2; ++ks) {
            const int ko = (ks * 64 + hi * 16) ^ sx;
            f16x8 af[4], bf[4];
#pragma unroll
            for (int mi = 0; mi < 4; ++mi)
                af[mi] = *(const f16x8*)(AsB + (wr * 64 + mi * 16 + ln) * 128 + ko);
#pragma unroll
            for (int ni = 0; ni < 4; ++ni)
                bf[ni] = *(const f16x8*)(BsB + (wc * 64 + ni * 16 + ln) * 128 + ko);
#pragma unroll
            for (int mi = 0; mi < 4; ++mi)
#pragma unroll
                for (int ni = 0; ni < 4; ++ni)
                    acc[mi][ni] = __builtin_amdgcn_mfma_f32_16x16x32_f16(
                        af[mi], bf[ni], acc[mi][ni], 0, 0, 0);
        }
    }

    // ---- epilogue: dist + fused argmin
    float bnv[4];
#pragma unroll
    for (int ni = 0; ni < 4; ++ni)
        bnv[ni] = Bn[c0 + wc * 64 + ni * 16 + ln];
    const int rbase = row0 + wr * 64 + hi * 4;

#pragma unroll
    for (int mi = 0; mi < 4; ++mi) {
#pragma unroll
        for (int r = 0; r < 4; ++r) {
            float an = An[rbase + mi * 16 + r];
            unsigned long long best = ~0ull;
#pragma unroll
            for (int ni = 0; ni < 4; ++ni) {
                float sim  = acc[mi][ni][r] * 0x1p-20f;   // exact descale
                float t    = an + bnv[ni];
                float dist = t - 2.0f * sim;
                unsigned code = (unsigned)(c0 + wc * 64 + ni * 16 + ln);
                unsigned long long p =
                    ((unsigned long long)__float_as_uint(dist) << 32) | code;
                best = p < best ? p : best;
            }
#pragma unroll
            for (int mm = 1; mm < 16; mm <<= 1) {
                unsigned long long o = __shfl_xor(best, mm);
                best = o < best ? o : best;
            }
            if (ln == 0) atomicMin(&bests[rbase + mi * 16 + r], best);
        }
    }
}

// ---------------------------------------------------------------- gather + loss partials
__global__ void vq_gather(const float* __restrict__ x, const float* __restrict__ et,
                          const unsigned long long* __restrict__ bests,
                          float* __restrict__ out, float* __restrict__ part) {
    __shared__ float wsum[4];
    int w    = threadIdx.x >> 6;
    int lane = threadIdx.x & 63;
    int row  = blockIdx.x * 4 + w;
    int k    = (int)(unsigned)(bests[row] & 0xffffffffull);
    float4 q  = *(const float4*)&et[(size_t)k * DIM + lane * 4];
    float4 xv = *(const float4*)&x[(size_t)row * DIM + lane * 4];
    *(float4*)&out[(size_t)row * DIM + lane * 4] = q;
    float d0 = q.x - xv.x, d1 = q.y - xv.y, d2 = q.z - xv.z, d3 = q.w - xv.w;
    float s = d0 * d0 + d1 * d1 + d2 * d2 + d3 * d3;
#pragma unroll
    for (int m = 1; m < 64; m <<= 1) s += __shfl_xor(s, m);
    if (lane == 0) wsum[w] = s;
    __syncthreads();
    if (threadIdx.x == 0) part[blockIdx.x] = wsum[0] + wsum[1] + wsum[2] + wsum[3];
}

// ---------------------------------------------------------------- finalize loss
__global__ void vq_finalize(const float* __restrict__ part, float* __restrict__ lossOut) {
    __shared__ float sm[256];
    float s = 0.0f;
    for (int i = threadIdx.x; i < 8192; i += 256) s += part[i];
    sm[threadIdx.x] = s;
    __syncthreads();
    for (int st = 128; st > 0; st >>= 1) {
        if (threadIdx.x < st) sm[threadIdx.x] += sm[threadIdx.x + st];
        __syncthreads();
    }
    if (threadIdx.x == 0)
        lossOut[0] = 1.25f * (sm[0] / 8388608.0f);
}

// ---------------------------------------------------------------- launch
extern "C" void kernel_launch(void* const* d_in, const int* in_sizes, int n_in,
                              void* d_out, int out_size, void* d_ws, size_t ws_size,
                              hipStream_t stream) {
    const float* x = (const float*)d_in[0];   // [32768, 256]
    const float* e = (const float*)d_in[1];   // [256, 4096]
    float* out = (float*)d_out;
    float* ws  = (float*)d_ws;

    float* et   = ws + WS_ET;
    float* bn   = ws + WS_BN;
    float* an   = ws + WS_AN;
    float* part = ws + WS_PART;
    unsigned long long* bests = (unsigned long long*)(ws + WS_BEST);
    f16*   Bp   = (f16*)(ws + WS_BP);

    vq_prep_b<<<256, 256, 0, stream>>>(e, Bp);
    vq_transpose<<<dim3(KCODES / 32, DIM / 32), 256, 0, stream>>>(e, et);
    vq_rownorm<<<N_ROWS / 4, 256, 0, stream>>>(x, an, N_ROWS);
    vq_rownorm<<<KCODES / 4, 256, 0, stream>>>(et, bn, KCODES);
    vq_init<<<N_ROWS / 256, 256, 0, stream>>>(bests);
    vq_main<<<8192, 256, 0, stream>>>(x, Bp, an, bn, bests);
    vq_gather<<<N_ROWS / 4, 256, 0, stream>>>(x, et, bests, out, part);
    vq_finalize<<<1, 256, 0, stream>>>(part, out + (size_t)N_ROWS * DIM);
}

// Round 3
// 371.868 us; speedup vs baseline: 2.9924x; 1.1038x over previous
//
#include <hip/hip_runtime.h>
#include <math.h>

typedef _Float16 f16;
typedef f16 f16x8 __attribute__((ext_vector_type(8)));
typedef float f32x4 __attribute__((ext_vector_type(4)));

#define N_ROWS 32768
#define DIM    256
#define KCODES 4096

// ws layout (float units)
#define WS_ET    0                           // et [4096][256] f32        (4 MB)
#define WS_BN    (WS_ET + KCODES*DIM)        // code norms [4096]
#define WS_AN    (WS_BN + KCODES)            // row norms [32768]
#define WS_PART  (WS_AN + N_ROWS)            // loss partials [8192]
#define WS_BEST  (WS_PART + 8192)            // u64 bests [32768] = 65536 floats
#define WS_BP    (WS_BEST + 65536)           // B' images  4 MB = 1048576 floats
#define WS_AP    (WS_BP + 1048576)           // A' images 32 MB = 8388608 floats
// total ~10.6M floats = 42.4 MB

// Image geometry: one chunk = [128 rows][64 f16 = 128 B], swizzled:
//   byte_in_row = (dd*2) ^ ((row & 7) << 4)
// Per-rb A' block: 131072 B  (H plane @0: 4 chunks x 16384; L plane @65536)
// Per-jb B' block: 131072 B  (EH plane @0; EL plane @65536)

// ---------------------------------------------------------------- helpers
__device__ __forceinline__ void gload16(const void* g, void* l) {
#if __has_builtin(__builtin_amdgcn_global_load_lds)
    __builtin_amdgcn_global_load_lds(
        (const __attribute__((address_space(1))) unsigned int*)g,
        (__attribute__((address_space(3))) unsigned int*)l, 16, 0, 0);
#else
    *(float4*)l = *(const float4*)g;
#endif
}

// ---------------------------------------------------------------- transpose (for gather + bn)
__global__ void vq_transpose(const float* __restrict__ e, float* __restrict__ et) {
    __shared__ float tile[32][33];
    int x = threadIdx.x & 31;
    int y = threadIdx.x >> 5;
    int k0 = blockIdx.x * 32;
    int d0 = blockIdx.y * 32;
#pragma unroll
    for (int yy = 0; yy < 32; yy += 8)
        tile[y + yy][x] = e[(d0 + y + yy) * KCODES + k0 + x];
    __syncthreads();
#pragma unroll
    for (int yy = 0; yy < 32; yy += 8)
        et[(k0 + y + yy) * DIM + d0 + x] = tile[x][y + yy];
}

// ---------------------------------------------------------------- row norms
__global__ void vq_rownorm(const float* __restrict__ src, float* __restrict__ out, int nrows) {
    int w    = threadIdx.x >> 6;
    int lane = threadIdx.x & 63;
    int row  = blockIdx.x * 4 + w;
    if (row >= nrows) return;
    float4 v = *(const float4*)&src[row * DIM + lane * 4];
    float  s = v.x * v.x + v.y * v.y + v.z * v.z + v.w * v.w;
#pragma unroll
    for (int m = 1; m < 64; m <<= 1) s += __shfl_xor(s, m);
    if (lane == 0) out[row] = s;
}

// ---------------------------------------------------------------- A' prep
// x [32768][256] f32 -> per-rb swizzled H/L chunk images.
// grid 256 blocks (1 per rb), 256 threads. Wave-coalesced float4 reads.
__global__ void vq_prep_a(const float* __restrict__ x, char* __restrict__ Ap) {
    const int t = threadIdx.x;
    const int lane = t & 63, w = t >> 6;
    const size_t row0 = (size_t)blockIdx.x * 128;
    char* base = Ap + (size_t)blockIdx.x * 131072;
    const int chunk = lane >> 4;
    const int dd2   = (lane & 15) * 8;       // byte offset of 4 f16
#pragma unroll 4
    for (int it = 0; it < 32; ++it) {
        const int m = it * 4 + w;
        float4 v = *(const float4*)&x[(row0 + m) * DIM + lane * 4];
        float vs[4] = { v.x, v.y, v.z, v.w };
        uint32_t hw[2], lw[2];
#pragma unroll
        for (int p = 0; p < 2; ++p) {
            uint32_t hword = 0, lword = 0;
#pragma unroll
            for (int j = 0; j < 2; ++j) {
                float s = vs[p * 2 + j] * 1024.0f;
                f16 h = (f16)s;
                f16 l = (f16)(s - (float)h);
                hword |= (uint32_t)__builtin_bit_cast(uint16_t, h) << (16 * j);
                lword |= (uint32_t)__builtin_bit_cast(uint16_t, l) << (16 * j);
            }
            hw[p] = hword; lw[p] = lword;
        }
        const int off = chunk * 16384 + m * 128 + (dd2 ^ ((m & 7) << 4));
        *(uint2*)(base + off)         = *(uint2*)hw;
        *(uint2*)(base + 65536 + off) = *(uint2*)lw;
    }
}

// ---------------------------------------------------------------- B' prep
// e [256][4096] f32 -> per-jb swizzled EH/EL chunk images.
// grid 128 blocks: jb = bid>>2, chunk c = bid&3 (64 d x 128 codes).
__global__ void vq_prep_b(const float* __restrict__ e, char* __restrict__ Bp) {
    __shared__ float lt[128][65];   // [n_loc][dd]
    const int t  = threadIdx.x;
    const int jb = blockIdx.x >> 2;
    const int c  = blockIdx.x & 3;
    const int d0 = c * 64, n0 = jb * 128;
    // coalesced load e[d0..d0+63][n0..n0+127] -> transposed LDS
#pragma unroll
    for (int it = 0; it < 8; ++it) {
        int linear = it * 256 + t;
        int drow = linear >> 5;            // 0..63
        int ncol = (linear & 31) * 4;      // 0..124
        float4 v = *(const float4*)&e[(size_t)(d0 + drow) * KCODES + n0 + ncol];
        lt[ncol + 0][drow] = v.x;
        lt[ncol + 1][drow] = v.y;
        lt[ncol + 2][drow] = v.z;
        lt[ncol + 3][drow] = v.w;
    }
    __syncthreads();
    char* ehbase = Bp + (size_t)jb * 131072 + c * 16384;
    const int n_loc = t >> 1;
    const int shalf = t & 1;
#pragma unroll
    for (int g = 0; g < 4; ++g) {
        const int dd8 = shalf * 32 + g * 8;
        uint32_t ehw[4], elw[4];
#pragma unroll
        for (int p = 0; p < 4; ++p) {
            uint32_t hword = 0, lword = 0;
#pragma unroll
            for (int j = 0; j < 2; ++j) {
                float s = lt[n_loc][dd8 + p * 2 + j] * 1024.0f;
                f16 h = (f16)s;
                f16 l = (f16)(s - (float)h);
                hword |= (uint32_t)__builtin_bit_cast(uint16_t, h) << (16 * j);
                lword |= (uint32_t)__builtin_bit_cast(uint16_t, l) << (16 * j);
            }
            ehw[p] = hword; elw[p] = lword;
        }
        const int off = n_loc * 128 + ((dd8 * 2) ^ ((n_loc & 7) << 4));
        *(uint4*)(ehbase + off)         = *(uint4*)ehw;
        *(uint4*)(ehbase + 65536 + off) = *(uint4*)elw;
    }
}

// ---------------------------------------------------------------- init bests
__global__ void vq_init(unsigned long long* __restrict__ bests) {
    int i = blockIdx.x * 256 + threadIdx.x;
    if (i < N_ROWS) bests[i] = ~0ull;
}

// ---------------------------------------------------------------- main MFMA GEMM + argmin
// sim*2^20 = H.EH + H.EL + L.EH  (l*l term dropped, ~4e-7 in dist units)
// 128 rows x 128 codes per block; per d-chunk (64 d): stage {A_H,A_L,B_EH},
// 64 MFMA; restage B_EL; 32 MFMA.
__global__ __launch_bounds__(256) void vq_main(
    const char* __restrict__ Ap, const char* __restrict__ Bp,
    const float* __restrict__ An, const float* __restrict__ Bn,
    unsigned long long* __restrict__ bests)
{
    __shared__ __align__(16) char AsH[16384];
    __shared__ __align__(16) char AsL[16384];
    __shared__ __align__(16) char Bs[16384];

    const int tid  = threadIdx.x;
    const int wid  = tid >> 6, lane = tid & 63;
    const int wr   = wid >> 1, wc = wid & 1;
    const int rb   = blockIdx.x & 255, jb = blockIdx.x >> 8;
    const int row0 = rb * 128, c0 = jb * 128;
    const int hi = lane >> 4, ln = lane & 15;
    const int sx = (lane & 7) << 4;

    const char* abase = Ap + (size_t)rb * 131072;
    const char* bbase = Bp + (size_t)jb * 131072;

    f32x4 acc[4][4] = {};

    for (int c = 0; c < 4; ++c) {
        __syncthreads();   // prior readers of AsH/AsL/Bs done
#pragma unroll
        for (int it = 0; it < 4; ++it) {
            const int o = it * 4096 + tid * 16;
            gload16(abase + c * 16384 + o,         AsH + o);
            gload16(abase + 65536 + c * 16384 + o, AsL + o);
            gload16(bbase + c * 16384 + o,         Bs + o);
        }
        __syncthreads();   // staging complete (vmcnt drained by barrier)

#pragma unroll
        for (int ks = 0; ks < 2; ++ks) {
            const int ko = (ks * 64 + hi * 16) ^ sx;
            f16x8 bf[4], ah[4], al[4];
#pragma unroll
            for (int ni = 0; ni < 4; ++ni)
                bf[ni] = *(const f16x8*)(Bs + (wc * 64 + ni * 16 + ln) * 128 + ko);
#pragma unroll
            for (int mi = 0; mi < 4; ++mi) {
                ah[mi] = *(const f16x8*)(AsH + (wr * 64 + mi * 16 + ln) * 128 + ko);
                al[mi] = *(const f16x8*)(AsL + (wr * 64 + mi * 16 + ln) * 128 + ko);
            }
#pragma unroll
            for (int mi = 0; mi < 4; ++mi)
#pragma unroll
                for (int ni = 0; ni < 4; ++ni)
                    acc[mi][ni] = __builtin_amdgcn_mfma_f32_16x16x32_f16(
                        ah[mi], bf[ni], acc[mi][ni], 0, 0, 0);
#pragma unroll
            for (int mi = 0; mi < 4; ++mi)
#pragma unroll
                for (int ni = 0; ni < 4; ++ni)
                    acc[mi][ni] = __builtin_amdgcn_mfma_f32_16x16x32_f16(
                        al[mi], bf[ni], acc[mi][ni], 0, 0, 0);
        }

        __syncthreads();   // done reading Bs
#pragma unroll
        for (int it = 0; it < 4; ++it) {
            const int o = it * 4096 + tid * 16;
            gload16(bbase + 65536 + c * 16384 + o, Bs + o);
        }
        __syncthreads();

#pragma unroll
        for (int ks = 0; ks < 2; ++ks) {
            const int ko = (ks * 64 + hi * 16) ^ sx;
            f16x8 bf[4], ah[4];
#pragma unroll
            for (int ni = 0; ni < 4; ++ni)
                bf[ni] = *(const f16x8*)(Bs + (wc * 64 + ni * 16 + ln) * 128 + ko);
#pragma unroll
            for (int mi = 0; mi < 4; ++mi)
                ah[mi] = *(const f16x8*)(AsH + (wr * 64 + mi * 16 + ln) * 128 + ko);
#pragma unroll
            for (int mi = 0; mi < 4; ++mi)
#pragma unroll
                for (int ni = 0; ni < 4; ++ni)
                    acc[mi][ni] = __builtin_amdgcn_mfma_f32_16x16x32_f16(
                        ah[mi], bf[ni], acc[mi][ni], 0, 0, 0);
        }
    }

    // ---- epilogue: dist + fused argmin
    float bnv[4];
#pragma unroll
    for (int ni = 0; ni < 4; ++ni)
        bnv[ni] = Bn[c0 + wc * 64 + ni * 16 + ln];
    const int rbase = row0 + wr * 64 + hi * 4;

#pragma unroll
    for (int mi = 0; mi < 4; ++mi) {
#pragma unroll
        for (int r = 0; r < 4; ++r) {
            float an = An[rbase + mi * 16 + r];
            unsigned long long best = ~0ull;
#pragma unroll
            for (int ni = 0; ni < 4; ++ni) {
                float sim  = acc[mi][ni][r] * 0x1p-20f;   // exact descale
                float t    = an + bnv[ni];
                float dist = t - 2.0f * sim;
                unsigned code = (unsigned)(c0 + wc * 64 + ni * 16 + ln);
                unsigned long long p =
                    ((unsigned long long)__float_as_uint(dist) << 32) | code;
                best = p < best ? p : best;
            }
#pragma unroll
            for (int mm = 1; mm < 16; mm <<= 1) {
                unsigned long long o = __shfl_xor(best, mm);
                best = o < best ? o : best;
            }
            if (ln == 0) atomicMin(&bests[rbase + mi * 16 + r], best);
        }
    }
}

// ---------------------------------------------------------------- gather + loss partials
__global__ void vq_gather(const float* __restrict__ x, const float* __restrict__ et,
                          const unsigned long long* __restrict__ bests,
                          float* __restrict__ out, float* __restrict__ part) {
    __shared__ float wsum[4];
    int w    = threadIdx.x >> 6;
    int lane = threadIdx.x & 63;
    int row  = blockIdx.x * 4 + w;
    int k    = (int)(unsigned)(bests[row] & 0xffffffffull);
    float4 q  = *(const float4*)&et[(size_t)k * DIM + lane * 4];
    float4 xv = *(const float4*)&x[(size_t)row * DIM + lane * 4];
    *(float4*)&out[(size_t)row * DIM + lane * 4] = q;
    float d0 = q.x - xv.x, d1 = q.y - xv.y, d2 = q.z - xv.z, d3 = q.w - xv.w;
    float s = d0 * d0 + d1 * d1 + d2 * d2 + d3 * d3;
#pragma unroll
    for (int m = 1; m < 64; m <<= 1) s += __shfl_xor(s, m);
    if (lane == 0) wsum[w] = s;
    __syncthreads();
    if (threadIdx.x == 0) part[blockIdx.x] = wsum[0] + wsum[1] + wsum[2] + wsum[3];
}

// ---------------------------------------------------------------- finalize loss
__global__ void vq_finalize(const float* __restrict__ part, float* __restrict__ lossOut) {
    __shared__ float sm[256];
    float s = 0.0f;
    for (int i = threadIdx.x; i < 8192; i += 256) s += part[i];
    sm[threadIdx.x] = s;
    __syncthreads();
    for (int st = 128; st > 0; st >>= 1) {
        if (threadIdx.x < st) sm[threadIdx.x] += sm[threadIdx.x + st];
        __syncthreads();
    }
    if (threadIdx.x == 0)
        lossOut[0] = 1.25f * (sm[0] / 8388608.0f);
}

// ---------------------------------------------------------------- launch
extern "C" void kernel_launch(void* const* d_in, const int* in_sizes, int n_in,
                              void* d_out, int out_size, void* d_ws, size_t ws_size,
                              hipStream_t stream) {
    const float* x = (const float*)d_in[0];   // [32768, 256]
    const float* e = (const float*)d_in[1];   // [256, 4096]
    float* out = (float*)d_out;
    float* ws  = (float*)d_ws;

    float* et   = ws + WS_ET;
    float* bn   = ws + WS_BN;
    float* an   = ws + WS_AN;
    float* part = ws + WS_PART;
    unsigned long long* bests = (unsigned long long*)(ws + WS_BEST);
    char*  Bp   = (char*)(ws + WS_BP);
    char*  Ap   = (char*)(ws + WS_AP);

    vq_prep_a<<<256, 256, 0, stream>>>(x, Ap);
    vq_prep_b<<<128, 256, 0, stream>>>(e, Bp);
    vq_transpose<<<dim3(KCODES / 32, DIM / 32), 256, 0, stream>>>(e, et);
    vq_rownorm<<<N_ROWS / 4, 256, 0, stream>>>(x, an, N_ROWS);
    vq_rownorm<<<KCODES / 4, 256, 0, stream>>>(et, bn, KCODES);
    vq_init<<<N_ROWS / 256, 256, 0, stream>>>(bests);
    vq_main<<<8192, 256, 0, stream>>>(Ap, Bp, an, bn, bests);
    vq_gather<<<N_ROWS / 4, 256, 0, stream>>>(x, et, bests, out, part);
    vq_finalize<<<1, 256, 0, stream>>>(part, out + (size_t)N_ROWS * DIM);
}